// Round 9
// baseline (621.550 us; speedup 1.0000x reference)
//
#include <hip/hip_runtime.h>
#include <hip/hip_bf16.h>
#include <stdint.h>

typedef __attribute__((ext_vector_type(8))) short short8;
typedef __attribute__((ext_vector_type(4))) float floatx4;

#define MFMA32K(a, b, c) __builtin_amdgcn_mfma_f32_16x16x32_bf16(a, b, c, 0, 0, 0)

constexpr int N_Q  = 8192;
constexpr int M_KV = 8192;
constexpr int DMID = 128;
constexpr int DV   = 256;

__device__ __forceinline__ unsigned short f2bf(float x) {
    unsigned u = __float_as_uint(x);
    u += 0x7fffu + ((u >> 16) & 1u);
    return (unsigned short)(u >> 16);
}

__device__ __forceinline__ short8 cvt_f8_bf8(float4 a, float4 b) {
    short8 r;
    r[0] = (short)f2bf(a.x); r[1] = (short)f2bf(a.y);
    r[2] = (short)f2bf(a.z); r[3] = (short)f2bf(a.w);
    r[4] = (short)f2bf(b.x); r[5] = (short)f2bf(b.y);
    r[6] = (short)f2bf(b.z); r[7] = (short)f2bf(b.w);
    return r;
}

// nonzero-byte -> 4-bit mask (bit i = byte i != 0)
__device__ __forceinline__ unsigned nz4(unsigned x) {
    unsigned nz = (((x & 0x7f7f7f7fu) + 0x7f7f7f7fu) | x) & 0x80808080u;
    unsigned a = (nz >> 7) & 0x01010101u;
    return (a * 0x01020408u) >> 24;
}

// ---------------------------------------------------------------------------
// Projections: dst[row] = src[row] @ W^T + bias, bf16, 16B-unit rotation
// within the row: unit' = (unit + row) & 15.
// ---------------------------------------------------------------------------
__global__ __launch_bounds__(256) void proj_kernel(
    const float* __restrict__ main_feat, const float* __restrict__ Wq, const float* __restrict__ bq,
    const float* __restrict__ other_feat, const float* __restrict__ Wk, const float* __restrict__ bk,
    unsigned short* __restrict__ Qw, unsigned short* __restrict__ Kw)
{
    const float* src;  const float* W;  const float* bias;  unsigned short* dst;
    if (blockIdx.y == 0) { src = main_feat;  W = Wq; bias = bq; dst = Qw; }
    else                 { src = other_feat; W = Wk; bias = bk; dst = Kw; }

    const int wave = threadIdx.x >> 6, lane = threadIdx.x & 63;
    const int n = lane & 15, quad = lane >> 4;
    const int row0 = blockIdx.x * 64 + wave * 16;

    short8 a[8];
    const float* ap = src + (size_t)(row0 + n) * 256 + quad * 8;
#pragma unroll
    for (int ks = 0; ks < 8; ++ks) {
        float4 x0 = *(const float4*)(ap + ks * 32);
        float4 x1 = *(const float4*)(ap + ks * 32 + 4);
        a[ks] = cvt_f8_bf8(x0, x1);
    }

    floatx4 acc[8];
#pragma unroll
    for (int nt = 0; nt < 8; ++nt) acc[nt] = floatx4{0.f, 0.f, 0.f, 0.f};

#pragma unroll
    for (int nt = 0; nt < 8; ++nt) {
        const float* wp = W + (size_t)(nt * 16 + n) * 256 + quad * 8;
#pragma unroll
        for (int ks = 0; ks < 8; ++ks) {
            float4 w0 = *(const float4*)(wp + ks * 32);
            float4 w1 = *(const float4*)(wp + ks * 32 + 4);
            short8 b = cvt_f8_bf8(w0, w1);
            acc[nt] = MFMA32K(a[ks], b, acc[nt]);
        }
    }

#pragma unroll
    for (int nt = 0; nt < 8; ++nt) {
        float bb = bias[nt * 16 + n];
#pragma unroll
        for (int reg = 0; reg < 4; ++reg) {
            int r = row0 + quad * 4 + reg;
            int c = nt * 16 + n;
            int phys = ((((c >> 3) + r) & 15) << 3) | (c & 7);
            dst[(size_t)r * DMID + phys] = f2bf(acc[nt][reg] + bb);
        }
    }
}

// ---------------------------------------------------------------------------
// Vt[d][col(m)] = fix[m] * other[m][d]; col = pc-permutation (kv=32e+16s+4q+j
// -> pc=32e+8q+4s+j) composed with 16B-unit rotation by d per 64-col group.
// ---------------------------------------------------------------------------
__global__ __launch_bounds__(256) void build_vt_kernel(
    const float* __restrict__ other_feat, const float* __restrict__ fix_feat,
    unsigned short* __restrict__ Vt)
{
    __shared__ unsigned short tile[64 * 72];
    const int t = threadIdx.x;
    const int m0 = blockIdx.x * 64, d0 = blockIdx.y * 64;

#pragma unroll
    for (int r = 0; r < 4; ++r) {
        int idx = r * 256 + t;
        int ml = idx >> 4, dl4 = (idx & 15) * 4;
        float4 v = *(const float4*)(other_feat + (size_t)(m0 + ml) * 256 + d0 + dl4);
        float f = fix_feat[m0 + ml];
        tile[(dl4 + 0) * 72 + ml] = f2bf(v.x * f);
        tile[(dl4 + 1) * 72 + ml] = f2bf(v.y * f);
        tile[(dl4 + 2) * 72 + ml] = f2bf(v.z * f);
        tile[(dl4 + 3) * 72 + ml] = f2bf(v.w * f);
    }
    __syncthreads();
#pragma unroll
    for (int r = 0; r < 8; ++r) {
        int dl = r * 8 + (t >> 5);
        int d = d0 + dl;
        int ml = (t & 31) * 2;
        int e = ml >> 5, s = (ml >> 4) & 1, q = (ml >> 2) & 3, j = ml & 3;
        int pc = e * 32 + q * 8 + s * 4 + j;
        int phys = ((((pc >> 3) + d) & 7) << 3) | (pc & 7);
        unsigned int v0 = tile[dl * 72 + ml];
        unsigned int v1 = tile[dl * 72 + ml + 1];
        *(unsigned int*)(Vt + (size_t)d * M_KV + m0 + phys) = v0 | (v1 << 16);
    }
}

// ---------------------------------------------------------------------------
// Flash attention body — NO-LDS / NO-BARRIER streaming form:
// K and Vt are L2-resident per XCD chunk (256 KB + 512 KB shared by 64
// blocks; stagger keeps the whole chunk hot), so LDS staging bought nothing
// but two vmcnt(0) barrier parks per iteration (common-mistake #7). QK reads
// K-fragments and PV reads Vt-fragments DIRECTLY from global (same per-lane
// address math as the old LDS layout, m0-offset). Each wave is an
// independent compiler-pipelined stream; compiler inserts per-use counted
// waits. Mask keeps R4's proven spill-free placement: issue post-softmax,
// compress at next iter top. Per-block KV phase stagger spreads HBM bursts.
// ESZ = mask element size (4: int32/f32 nonzero; 1: bool/uint8).
// BM=128 (4 waves x 32 q-rows), all-16x16x32 MFMA, S^T form, no online max.
// ---------------------------------------------------------------------------
template<int ESZ>
__device__ __forceinline__ void flash_body(
    const unsigned short* __restrict__ Qw, const unsigned short* __restrict__ Kw,
    const unsigned short* __restrict__ Vt, const unsigned int* __restrict__ mask,
    unsigned short* __restrict__ Opart, float* __restrict__ Lpart,
    int nsplit, int lgNs)
{
    const int L = blockIdx.x + gridDim.x * blockIdx.y;
    const int ly = L & (nsplit - 1);      // L&7 == XCD id under round-robin
    const int lx = L >> lgNs;             // -> per-XCD L2-resident K/V chunk
    const int chunkLen = M_KV >> lgNs;
    const int mBeg = ly * chunkLen;
    const int iters = chunkLen / 64;
    const int phase = lx & (iters - 1);   // per-block start tile (iters is pow2)
    const int tid = threadIdx.x;
    const int wave = tid >> 6, lane = tid & 63, n = lane & 15, quad = lane >> 4;
    const int qrow0 = lx * 128 + wave * 32;
    constexpr float SC = 0.08838834764831845f * 1.4426950408889634f; // scale*log2(e)

    auto mcol = [&](int it) {
        int idx = it + phase;
        if (idx >= iters) idx -= iters;
        return mBeg + idx * 64;
    };

    // Q fragments (rotated layout: unit' = (unit + row) & 15)
    short8 qf[2][4];
#pragma unroll
    for (int qt = 0; qt < 2; ++qt)
#pragma unroll
        for (int db = 0; db < 4; ++db) {
            int row = qrow0 + qt * 16 + n;
            int phys = (db * 4 + quad + row) & 15;
            qf[qt][db] = *(const short8*)(Qw + (size_t)row * DMID + phys * 8);
        }

    floatx4 Oacc[2][16];
#pragma unroll
    for (int qt = 0; qt < 2; ++qt)
#pragma unroll
        for (int dt = 0; dt < 16; ++dt) Oacc[qt][dt] = floatx4{0.f, 0.f, 0.f, 0.f};

    float lrow[2] = {0.f, 0.f};

    const int kqn = quad + n;

    // raw-mask prefetch registers (live post-softmax..next-iter-top only)
    uint4    mv4[2][4];   // ESZ==4: 16 elems/lane (cols m0+kvt*16+quad*4+j)
    unsigned mv1[2][4];   // ESZ==1: same cols, 4 bytes per dword

    auto load_mask = [&](int m0l) {
#pragma unroll
        for (int qt = 0; qt < 2; ++qt) {
            const size_t row = (size_t)(qrow0 + qt * 16 + n);
            if constexpr (ESZ == 4) {
                const unsigned* mp = mask + row * M_KV + m0l + quad * 4;
#pragma unroll
                for (int kvt = 0; kvt < 4; ++kvt)
                    mv4[qt][kvt] = *(const uint4*)(mp + kvt * 16);
            } else {
                const unsigned* mp = mask + row * (M_KV / 4) + (m0l >> 2) + quad;
#pragma unroll
                for (int kvt = 0; kvt < 4; ++kvt)
                    mv1[qt][kvt] = mp[kvt * 4];
            }
        }
    };

    // prologue: mask(tile 0) prefetch
    load_mask(mcol(0));

    for (int it = 0; it < iters; ++it) {
        const int m0 = mcol(it);

        // compress mask regs -> 16 predicate bits per lane (bit kvt*4+j)
        unsigned wq[2];
#pragma unroll
        for (int qt = 0; qt < 2; ++qt) {
            unsigned b = 0;
            if constexpr (ESZ == 4) {
#pragma unroll
                for (int kvt = 0; kvt < 4; ++kvt) {
                    const unsigned* c = (const unsigned*)&mv4[qt][kvt];
#pragma unroll
                    for (int j = 0; j < 4; ++j)
                        b |= (c[j] != 0u ? 1u : 0u) << (kvt * 4 + j);
                }
            } else {
#pragma unroll
                for (int kvt = 0; kvt < 4; ++kvt)
                    b |= nz4(mv1[qt][kvt]) << (kvt * 4);
            }
            wq[qt] = b;
        }

        // ---- S^T = K Q^T (kv = 16kvt + 4quad + reg, q = n) ----
        // K-fragments read directly from L2-hot Kw (rotated row layout).
        floatx4 ST[4][2];
        __builtin_amdgcn_s_setprio(1);
#pragma unroll
        for (int kvt = 0; kvt < 4; ++kvt) {
            const unsigned short* krow = Kw + (size_t)(m0 + kvt * 16 + n) * DMID;
            short8 a0 = *(const short8*)(krow + (((kqn + 0) & 15) << 3));
            short8 a1 = *(const short8*)(krow + (((kqn + 4) & 15) << 3));
            short8 a2 = *(const short8*)(krow + (((kqn + 8) & 15) << 3));
            short8 a3 = *(const short8*)(krow + (((kqn + 12) & 15) << 3));
#pragma unroll
            for (int qt = 0; qt < 2; ++qt) {
                floatx4 s = floatx4{0.f, 0.f, 0.f, 0.f};
                s = MFMA32K(a0, qf[qt][0], s);
                s = MFMA32K(a1, qf[qt][1], s);
                s = MFMA32K(a2, qf[qt][2], s);
                s = MFMA32K(a3, qf[qt][3], s);
                ST[kvt][qt] = s;
            }
        }
        __builtin_amdgcn_s_setprio(0);

        // ---- p = exp2(s*SC), 0 where masked; pack to A-frags ----
        short8 pf8[2][2];
#pragma unroll
        for (int qt = 0; qt < 2; ++qt) {
            const unsigned x = wq[qt];
            float lacc = 0.f;
#pragma unroll
            for (int kvt = 0; kvt < 4; ++kvt) {
                int e = kvt >> 1, s = kvt & 1;
                float p[4];
#pragma unroll
                for (int j = 0; j < 4; ++j) {
                    float v = __builtin_amdgcn_exp2f(ST[kvt][qt][j] * SC);
                    p[j] = ((x >> (kvt * 4 + j)) & 1u) ? 0.f : v;
                    lacc += p[j];
                }
                __hip_bfloat162 h0 = __float22bfloat162_rn(make_float2(p[0], p[1]));
                __hip_bfloat162 h1 = __float22bfloat162_rn(make_float2(p[2], p[3]));
                unsigned u0, u1;
                __builtin_memcpy(&u0, &h0, 4);
                __builtin_memcpy(&u1, &h1, 4);
                ((unsigned*)&pf8[qt][e])[s * 2 + 0] = u0;
                ((unsigned*)&pf8[qt][e])[s * 2 + 1] = u1;
            }
            lrow[qt] += lacc;
        }

        // mask(it+1) prefetch (R4's proven placement: live through PV only)
        if (it + 1 < iters) load_mask(mcol(it + 1));

        // ---- O += P V (rotated contiguous b128 directly from L2-hot Vt) ----
        __builtin_amdgcn_s_setprio(1);
#pragma unroll
        for (int e = 0; e < 2; ++e) {
#pragma unroll
            for (int dt = 0; dt < 16; ++dt) {
                const unsigned short* vrow = Vt + (size_t)(dt * 16 + n) * M_KV + m0;
                short8 bv = *(const short8*)(vrow + (((e * 4 + quad + n) & 7) << 3));
                Oacc[0][dt] = MFMA32K(pf8[0][e], bv, Oacc[0][dt]);
                Oacc[1][dt] = MFMA32K(pf8[1][e], bv, Oacc[1][dt]);
            }
        }
        __builtin_amdgcn_s_setprio(0);
    }

    // ---- epilogue: bf16 partials + cross-quad l reduction ----
    const size_t obase = (size_t)ly * N_Q * DV;
#pragma unroll
    for (int qt = 0; qt < 2; ++qt)
#pragma unroll
        for (int dt = 0; dt < 16; ++dt)
#pragma unroll
            for (int reg = 0; reg < 4; ++reg) {
                int gr = qrow0 + qt * 16 + quad * 4 + reg;
                Opart[obase + (size_t)gr * DV + dt * 16 + n] = f2bf(Oacc[qt][dt][reg]);
            }
#pragma unroll
    for (int qt = 0; qt < 2; ++qt) {
        float r = lrow[qt];
        r += __shfl_xor(r, 16);
        r += __shfl_xor(r, 32);
        if (quad == 0)
            Lpart[ly * N_Q + qrow0 + qt * 16 + n] = r;
    }
}

// ---------------------------------------------------------------------------
// Flash kernel: in-device mask-dtype detection (element count can't
// distinguish 1B vs 4B storage host-side), then dispatch to matching body.
// No LDS, no barriers.
// ---------------------------------------------------------------------------
__global__ __launch_bounds__(256, 2) void flash_kernel(
    const unsigned short* __restrict__ Qw, const unsigned short* __restrict__ Kw,
    const unsigned short* __restrict__ Vt, const unsigned int* __restrict__ mask,
    unsigned short* __restrict__ Opart, float* __restrict__ Lpart,
    int nsplit, int lgNs)
{
    // dtype detect on first 64 words (L2-hot; identical across waves/blocks):
    // f32 1.0 pattern -> 4-byte; word>1 -> packed uint8; else int32 -> 4-byte
    unsigned w0 = mask[threadIdx.x & 63];
    bool isf = (w0 == 0x3f800000u);
    bool isb = (w0 > 1u) && !isf;
    bool wide = (__ballot(isf) != 0ull) || (__ballot(isb) == 0ull);

    if (wide)
        flash_body<4>(Qw, Kw, Vt, mask, Opart, Lpart, nsplit, lgNs);
    else
        flash_body<1>(Qw, Kw, Vt, mask, Opart, Lpart, nsplit, lgNs);
}

// ---------------------------------------------------------------------------
// Combine: out = (sum_c O_c) / (sum_c l_c).
// ---------------------------------------------------------------------------
__global__ __launch_bounds__(256) void combine_kernel(
    const unsigned short* __restrict__ Opart, const float* __restrict__ Lpart,
    float* __restrict__ out, int nsplit)
{
    const int row = blockIdx.x, d = threadIdx.x;
    float L = 0.f, o = 0.f;
    for (int c = 0; c < nsplit; ++c) {
        L += Lpart[c * N_Q + row];
        unsigned int b = Opart[((size_t)c * N_Q + row) * DV + d];
        o += __uint_as_float(b << 16);
    }
    out[(size_t)row * DV + d] = o / L;
}

// ---------------------------------------------------------------------------
extern "C" void kernel_launch(void* const* d_in, const int* in_sizes, int n_in,
                              void* d_out, int out_size, void* d_ws, size_t ws_size,
                              hipStream_t stream)
{
    const float* main_feat  = (const float*)d_in[0];
    const float* other_feat = (const float*)d_in[1];
    const float* fix_feat   = (const float*)d_in[2];
    const void*  mask       = d_in[3];
    const float* Wq         = (const float*)d_in[4];
    const float* bq         = (const float*)d_in[5];
    const float* Wk         = (const float*)d_in[6];
    const float* bk         = (const float*)d_in[7];
    float* out = (float*)d_out;

    char* ws = (char*)d_ws;
    unsigned short* Qw = (unsigned short*)(ws);                         // 2 MB
    unsigned short* Kw = (unsigned short*)(ws + (1ull << 21));          // 2 MB
    unsigned short* Vt = (unsigned short*)(ws + (2ull << 21));          // 4 MB
    float* Lpart = (float*)(ws + (16ull << 20) + 2048);

    const size_t base = (16ull << 20) + 2048;
    auto need = [&](int ns) {
        return base + (size_t)ns * N_Q * 4 + (size_t)ns * N_Q * DV * 2;
    };
    int nsplit = 1, lgNs = 0;
    if (ws_size >= need(8))      { nsplit = 8; lgNs = 3; }
    else if (ws_size >= need(4)) { nsplit = 4; lgNs = 2; }
    else if (ws_size >= need(2)) { nsplit = 2; lgNs = 1; }

    unsigned short* Opart = (unsigned short*)(Lpart + (size_t)nsplit * N_Q);

    hipLaunchKernelGGL(proj_kernel, dim3(128, 2), dim3(256), 0, stream,
                       main_feat, Wq, bq, other_feat, Wk, bk, Qw, Kw);
    hipLaunchKernelGGL(build_vt_kernel, dim3(128, 4), dim3(256), 0, stream,
                       other_feat, fix_feat, Vt);
    hipLaunchKernelGGL(flash_kernel, dim3(64, nsplit), dim3(256), 0, stream,
                       Qw, Kw, Vt, (const unsigned int*)mask, Opart, Lpart, nsplit, lgNs);
    hipLaunchKernelGGL(combine_kernel, dim3(N_Q), dim3(256), 0, stream,
                       Opart, Lpart, out, nsplit);
}

// Round 11
// 535.235 us; speedup vs baseline: 1.1613x; 1.1613x over previous
//
#include <hip/hip_runtime.h>
#include <hip/hip_bf16.h>
#include <stdint.h>

typedef __attribute__((ext_vector_type(8))) short short8;
typedef __attribute__((ext_vector_type(4))) float floatx4;

#define MFMA32K(a, b, c) __builtin_amdgcn_mfma_f32_16x16x32_bf16(a, b, c, 0, 0, 0)

constexpr int N_Q  = 8192;
constexpr int M_KV = 8192;
constexpr int DMID = 128;
constexpr int DV   = 256;

__device__ __forceinline__ unsigned short f2bf(float x) {
    unsigned u = __float_as_uint(x);
    u += 0x7fffu + ((u >> 16) & 1u);
    return (unsigned short)(u >> 16);
}

__device__ __forceinline__ short8 cvt_f8_bf8(float4 a, float4 b) {
    short8 r;
    r[0] = (short)f2bf(a.x); r[1] = (short)f2bf(a.y);
    r[2] = (short)f2bf(a.z); r[3] = (short)f2bf(a.w);
    r[4] = (short)f2bf(b.x); r[5] = (short)f2bf(b.y);
    r[6] = (short)f2bf(b.z); r[7] = (short)f2bf(b.w);
    return r;
}

// async global->LDS, 16B per lane; lds dst is wave-uniform (HW adds lane*16)
__device__ __forceinline__ void gl_lds16(const unsigned short* g, unsigned short* l) {
    __builtin_amdgcn_global_load_lds(
        (const __attribute__((address_space(1))) unsigned int*)g,
        (__attribute__((address_space(3))) unsigned int*)l, 16, 0, 0);
}

// nonzero-byte -> 4-bit mask (bit i = byte i != 0)
__device__ __forceinline__ unsigned nz4(unsigned x) {
    unsigned nz = (((x & 0x7f7f7f7fu) + 0x7f7f7f7fu) | x) & 0x80808080u;
    unsigned a = (nz >> 7) & 0x01010101u;
    return (a * 0x01020408u) >> 24;
}

// ---------------------------------------------------------------------------
// Projections: dst[row] = src[row] @ W^T + bias, bf16, 16B-unit rotation
// within the row: unit' = (unit + row) & 15.
// ---------------------------------------------------------------------------
__global__ __launch_bounds__(256) void proj_kernel(
    const float* __restrict__ main_feat, const float* __restrict__ Wq, const float* __restrict__ bq,
    const float* __restrict__ other_feat, const float* __restrict__ Wk, const float* __restrict__ bk,
    unsigned short* __restrict__ Qw, unsigned short* __restrict__ Kw)
{
    const float* src;  const float* W;  const float* bias;  unsigned short* dst;
    if (blockIdx.y == 0) { src = main_feat;  W = Wq; bias = bq; dst = Qw; }
    else                 { src = other_feat; W = Wk; bias = bk; dst = Kw; }

    const int wave = threadIdx.x >> 6, lane = threadIdx.x & 63;
    const int n = lane & 15, quad = lane >> 4;
    const int row0 = blockIdx.x * 64 + wave * 16;

    short8 a[8];
    const float* ap = src + (size_t)(row0 + n) * 256 + quad * 8;
#pragma unroll
    for (int ks = 0; ks < 8; ++ks) {
        float4 x0 = *(const float4*)(ap + ks * 32);
        float4 x1 = *(const float4*)(ap + ks * 32 + 4);
        a[ks] = cvt_f8_bf8(x0, x1);
    }

    floatx4 acc[8];
#pragma unroll
    for (int nt = 0; nt < 8; ++nt) acc[nt] = floatx4{0.f, 0.f, 0.f, 0.f};

#pragma unroll
    for (int nt = 0; nt < 8; ++nt) {
        const float* wp = W + (size_t)(nt * 16 + n) * 256 + quad * 8;
#pragma unroll
        for (int ks = 0; ks < 8; ++ks) {
            float4 w0 = *(const float4*)(wp + ks * 32);
            float4 w1 = *(const float4*)(wp + ks * 32 + 4);
            short8 b = cvt_f8_bf8(w0, w1);
            acc[nt] = MFMA32K(a[ks], b, acc[nt]);
        }
    }

#pragma unroll
    for (int nt = 0; nt < 8; ++nt) {
        float bb = bias[nt * 16 + n];
#pragma unroll
        for (int reg = 0; reg < 4; ++reg) {
            int r = row0 + quad * 4 + reg;
            int c = nt * 16 + n;
            int phys = ((((c >> 3) + r) & 15) << 3) | (c & 7);
            dst[(size_t)r * DMID + phys] = f2bf(acc[nt][reg] + bb);
        }
    }
}

// ---------------------------------------------------------------------------
// Vt[d][col(m)] = fix[m] * other[m][d]; col = pc-permutation (kv=32e+16s+4q+j
// -> pc=32e+8q+4s+j) composed with 16B-unit rotation by d per 64-col group.
// ---------------------------------------------------------------------------
__global__ __launch_bounds__(256) void build_vt_kernel(
    const float* __restrict__ other_feat, const float* __restrict__ fix_feat,
    unsigned short* __restrict__ Vt)
{
    __shared__ unsigned short tile[64 * 72];
    const int t = threadIdx.x;
    const int m0 = blockIdx.x * 64, d0 = blockIdx.y * 64;

#pragma unroll
    for (int r = 0; r < 4; ++r) {
        int idx = r * 256 + t;
        int ml = idx >> 4, dl4 = (idx & 15) * 4;
        float4 v = *(const float4*)(other_feat + (size_t)(m0 + ml) * 256 + d0 + dl4);
        float f = fix_feat[m0 + ml];
        tile[(dl4 + 0) * 72 + ml] = f2bf(v.x * f);
        tile[(dl4 + 1) * 72 + ml] = f2bf(v.y * f);
        tile[(dl4 + 2) * 72 + ml] = f2bf(v.z * f);
        tile[(dl4 + 3) * 72 + ml] = f2bf(v.w * f);
    }
    __syncthreads();
#pragma unroll
    for (int r = 0; r < 8; ++r) {
        int dl = r * 8 + (t >> 5);
        int d = d0 + dl;
        int ml = (t & 31) * 2;
        int e = ml >> 5, s = (ml >> 4) & 1, q = (ml >> 2) & 3, j = ml & 3;
        int pc = e * 32 + q * 8 + s * 4 + j;
        int phys = ((((pc >> 3) + d) & 7) << 3) | (pc & 7);
        unsigned int v0 = tile[dl * 72 + ml];
        unsigned int v1 = tile[dl * 72 + ml + 1];
        *(unsigned int*)(Vt + (size_t)d * M_KV + m0 + phys) = v0 | (v1 << 16);
    }
}

// ---------------------------------------------------------------------------
// Flash attention body — 8-wave (512-thread) counted-vmcnt pipeline.
// Per wave: 16 q-rows (Oacc = 64 AGPR; ~128 unified regs -> targets 2
// blocks/CU = 16 waves). Per-iteration VMEM per wave, pinned order:
//   Vt(it) DMA [4] ; K(it+1) DMA [2] ; SGB ; compress(it) [counted wait on
//   mask(it), the 4 oldest] ; SGB ; mask(it+1) loads [4] ; SGB
//   QK ; softmax
//   beta: vmcnt(4)+lgkm(0)+barrier  -> drains Vt+K, masks keep flying
//         (vmcnt(0) last iter)
//   PV
//   end:  lgkm(0)+barrier           -> PV reads done before next Vt DMA
// R10's bug (compress AFTER load_mask overwrote mv4 -> wrong predicates) is
// fixed by this order; sched_barrier(0) pins prevent the scheduler from
// hoisting renamed mask loads above the DMAs (would corrupt beta's count).
// ESZ = mask element size (4: int32/f32 nonzero; 1: bool/uint8).
// BM=128 (8 waves x 16 rows), K double-buffered, Vt single-buffered,
// S^T form, all-16x16x32 MFMA, pc-permuted Vt, KV phase stagger (R8 win).
// LDS 64 KB.
// ---------------------------------------------------------------------------
template<int ESZ>
__device__ __forceinline__ void flash_body(
    const unsigned short* __restrict__ Qw, const unsigned short* __restrict__ Kw,
    const unsigned short* __restrict__ Vt, const unsigned int* __restrict__ mask,
    unsigned short* __restrict__ Opart, float* __restrict__ Lpart,
    int nsplit, int lgNs,
    unsigned short* k_lds /* 2 x 64 x 128 */, unsigned short* vt_lds /* 256 x 64 */)
{
    const int L = blockIdx.x + gridDim.x * blockIdx.y;
    const int ly = L & (nsplit - 1);      // L&7 == XCD id under round-robin
    const int lx = L >> lgNs;             // -> per-XCD L2-resident K/V chunk
    const int chunkLen = M_KV >> lgNs;
    const int mBeg = ly * chunkLen;
    const int iters = chunkLen / 64;
    const int phase = lx & (iters - 1);   // per-block start tile (iters is pow2)
    const int tid = threadIdx.x;
    const int wave = tid >> 6, lane = tid & 63, n = lane & 15, quad = lane >> 4;
    const int qrow0 = lx * 128 + wave * 16;   // 16 q-rows per wave
    constexpr float SC = 0.08838834764831845f * 1.4426950408889634f; // scale*log2(e)

    auto mcol = [&](int it) {
        int idx = it + phase;
        if (idx >= iters) idx -= iters;
        return mBeg + idx * 64;
    };

    // Q fragments (rotated layout: unit' = (unit + row) & 15)
    short8 qf[4];
#pragma unroll
    for (int db = 0; db < 4; ++db) {
        int row = qrow0 + n;
        int phys = (db * 4 + quad + row) & 15;
        qf[db] = *(const short8*)(Qw + (size_t)row * DMID + phys * 8);
    }

    floatx4 Oacc[16];
#pragma unroll
    for (int dt = 0; dt < 16; ++dt) Oacc[dt] = floatx4{0.f, 0.f, 0.f, 0.f};

    float lrow = 0.f;

    // staging invariants (8-wave coverage)
    const unsigned short* kg = Kw + (size_t)(wave * 4 + (lane >> 4)) * DMID + (lane & 15) * 8;
    const unsigned short* vg = Vt + (size_t)(wave * 8 + (lane >> 3)) * M_KV + (lane & 7) * 8;
    const int kqn = quad + n;

    // raw-mask prefetch regs (single q-tile: 4 loads, 16 VGPR)
    uint4    mv4[4];
    unsigned mv1[4];

    auto load_mask = [&](int m0l) {
        const size_t row = (size_t)(qrow0 + n);
        if constexpr (ESZ == 4) {
            const unsigned* mp = mask + row * M_KV + m0l + quad * 4;
#pragma unroll
            for (int kvt = 0; kvt < 4; ++kvt)
                mv4[kvt] = *(const uint4*)(mp + kvt * 16);
        } else {
            const unsigned* mp = mask + row * (M_KV / 4) + (m0l >> 2) + quad;
#pragma unroll
            for (int kvt = 0; kvt < 4; ++kvt)
                mv1[kvt] = mp[kvt * 4];
        }
    };

    // prologue: K(0) DMA [2] (pinned first), mask(0) [4] (pinned after);
    // vmcnt(4) drains K only, masks keep flying into iter 0's compress.
#pragma unroll
    for (int r = 0; r < 2; ++r)
        gl_lds16(kg + (size_t)(mcol(0) + r * 32) * DMID, &k_lds[wave * 512 + r * 4096]);
    __builtin_amdgcn_sched_barrier(0);
    load_mask(mcol(0));
    __builtin_amdgcn_sched_barrier(0);
    asm volatile("s_waitcnt vmcnt(4)\n\ts_barrier" ::: "memory");

    for (int it = 0; it < iters; ++it) {
        const int m0 = mcol(it);
        const unsigned short* kbuf = k_lds + (it & 1) * 8192;

        // ---- issue DMAs (oldest in vmcnt queue after masks(it)) ----
#pragma unroll
        for (int r = 0; r < 4; ++r)                       // Vt(it) [4]
            gl_lds16(vg + (size_t)(r * 64) * M_KV + m0, &vt_lds[wave * 512 + r * 4096]);
        const bool more = (it + 1 < iters);
        if (more) {
            const int m1 = mcol(it + 1);
            unsigned short* knext = k_lds + ((it + 1) & 1) * 8192 + wave * 512;
#pragma unroll
            for (int r = 0; r < 2; ++r)                   // K(it+1) [2]
                gl_lds16(kg + (size_t)(m1 + r * 32) * DMID, knext + r * 4096);
        }
        __builtin_amdgcn_sched_barrier(0);

        // ---- compress mask(it) (loaded LAST iteration; counted wait on the
        // 4 oldest outstanding loads) -> 16 predicate bits ----
        unsigned wq = 0;
        if constexpr (ESZ == 4) {
#pragma unroll
            for (int kvt = 0; kvt < 4; ++kvt) {
                const unsigned* c = (const unsigned*)&mv4[kvt];
#pragma unroll
                for (int j = 0; j < 4; ++j)
                    wq |= (c[j] != 0u ? 1u : 0u) << (kvt * 4 + j);
            }
        } else {
#pragma unroll
            for (int kvt = 0; kvt < 4; ++kvt)
                wq |= nz4(mv1[kvt]) << (kvt * 4);
        }
        __builtin_amdgcn_sched_barrier(0);

        // ---- NOW safe to issue mask(it+1) into mv regs (newest in queue)
        if (more) load_mask(mcol(it + 1));
        __builtin_amdgcn_sched_barrier(0);

        // ---- S^T = K Q^T (kv = 16kvt + 4quad + reg, q = n) ----
        floatx4 ST[4];
        __builtin_amdgcn_s_setprio(1);
#pragma unroll
        for (int kvt = 0; kvt < 4; ++kvt) {
            const int rowoff = (kvt * 16 + n) * DMID;
            short8 a0 = *(const short8*)&kbuf[rowoff + (((kqn + 0) & 15) << 3)];
            short8 a1 = *(const short8*)&kbuf[rowoff + (((kqn + 4) & 15) << 3)];
            short8 a2 = *(const short8*)&kbuf[rowoff + (((kqn + 8) & 15) << 3)];
            short8 a3 = *(const short8*)&kbuf[rowoff + (((kqn + 12) & 15) << 3)];
            floatx4 s = floatx4{0.f, 0.f, 0.f, 0.f};
            s = MFMA32K(a0, qf[0], s);
            s = MFMA32K(a1, qf[1], s);
            s = MFMA32K(a2, qf[2], s);
            s = MFMA32K(a3, qf[3], s);
            ST[kvt] = s;
        }
        __builtin_amdgcn_s_setprio(0);

        // ---- p = exp2(s*SC), 0 where masked; pack to A-frags ----
        short8 pf8[2];
#pragma unroll
        for (int kvt = 0; kvt < 4; ++kvt) {
            int e = kvt >> 1, s = kvt & 1;
            float p[4];
#pragma unroll
            for (int j = 0; j < 4; ++j) {
                float v = __builtin_amdgcn_exp2f(ST[kvt][j] * SC);
                p[j] = ((wq >> (kvt * 4 + j)) & 1u) ? 0.f : v;
                lrow += p[j];
            }
            __hip_bfloat162 h0 = __float22bfloat162_rn(make_float2(p[0], p[1]));
            __hip_bfloat162 h1 = __float22bfloat162_rn(make_float2(p[2], p[3]));
            unsigned u0, u1;
            __builtin_memcpy(&u0, &h0, 4);
            __builtin_memcpy(&u1, &h1, 4);
            ((unsigned*)&pf8[e])[s * 2 + 0] = u0;
            ((unsigned*)&pf8[e])[s * 2 + 1] = u1;
        }

        // beta: drain Vt(it)+K(it+1) (6 oldest of 10), masks stay in flight
        if (more)
            asm volatile("s_waitcnt vmcnt(4) lgkmcnt(0)\n\ts_barrier" ::: "memory");
        else
            asm volatile("s_waitcnt vmcnt(0) lgkmcnt(0)\n\ts_barrier" ::: "memory");

        // ---- O += P V (rotated contiguous b128 from vt_lds) ----
        __builtin_amdgcn_s_setprio(1);
#pragma unroll
        for (int e = 0; e < 2; ++e) {
#pragma unroll
            for (int dt = 0; dt < 16; ++dt) {
                const int vb = (dt * 16 + n) * 64 + (((e * 4 + quad + n) & 7) << 3);
                short8 bv = *(const short8*)&vt_lds[vb];
                Oacc[dt] = MFMA32K(pf8[e], bv, Oacc[dt]);
            }
        }
        __builtin_amdgcn_s_setprio(0);

        // end: all waves' PV reads done before next iteration's Vt DMA writes
        asm volatile("s_waitcnt lgkmcnt(0)\n\ts_barrier" ::: "memory");
    }

    // ---- epilogue: bf16 partials + cross-quad l reduction ----
    const size_t obase = (size_t)ly * N_Q * DV;
#pragma unroll
    for (int dt = 0; dt < 16; ++dt)
#pragma unroll
        for (int reg = 0; reg < 4; ++reg) {
            int gr = qrow0 + quad * 4 + reg;
            Opart[obase + (size_t)gr * DV + dt * 16 + n] = f2bf(Oacc[dt][reg]);
        }
    {
        float r = lrow;
        r += __shfl_xor(r, 16);
        r += __shfl_xor(r, 32);
        if (quad == 0)
            Lpart[ly * N_Q + qrow0 + n] = r;
    }
}

// ---------------------------------------------------------------------------
// Flash kernel: in-device mask-dtype detection (element count can't
// distinguish 1B vs 4B storage host-side), then dispatch to matching body.
// Both bodies share the kernel-scope LDS (64 KB).
// ---------------------------------------------------------------------------
__global__ __launch_bounds__(512, 4) void flash_kernel(
    const unsigned short* __restrict__ Qw, const unsigned short* __restrict__ Kw,
    const unsigned short* __restrict__ Vt, const unsigned int* __restrict__ mask,
    unsigned short* __restrict__ Opart, float* __restrict__ Lpart,
    int nsplit, int lgNs)
{
    __shared__ __align__(16) unsigned short k_lds[2][64 * 128];  // 2 x 16 KB
    __shared__ __align__(16) unsigned short vt_lds[256 * 64];    // 32 KB

    // dtype detect on first 64 words (L2-hot; identical across waves/blocks):
    // f32 1.0 pattern -> 4-byte; word>1 -> packed uint8; else int32 -> 4-byte
    unsigned w0 = mask[threadIdx.x & 63];
    bool isf = (w0 == 0x3f800000u);
    bool isb = (w0 > 1u) && !isf;
    bool wide = (__ballot(isf) != 0ull) || (__ballot(isb) == 0ull);

    if (wide)
        flash_body<4>(Qw, Kw, Vt, mask, Opart, Lpart, nsplit, lgNs,
                      &k_lds[0][0], vt_lds);
    else
        flash_body<1>(Qw, Kw, Vt, mask, Opart, Lpart, nsplit, lgNs,
                      &k_lds[0][0], vt_lds);
}

// ---------------------------------------------------------------------------
// Combine: out = (sum_c O_c) / (sum_c l_c).
// ---------------------------------------------------------------------------
__global__ __launch_bounds__(256) void combine_kernel(
    const unsigned short* __restrict__ Opart, const float* __restrict__ Lpart,
    float* __restrict__ out, int nsplit)
{
    const int row = blockIdx.x, d = threadIdx.x;
    float L = 0.f, o = 0.f;
    for (int c = 0; c < nsplit; ++c) {
        L += Lpart[c * N_Q + row];
        unsigned int b = Opart[((size_t)c * N_Q + row) * DV + d];
        o += __uint_as_float(b << 16);
    }
    out[(size_t)row * DV + d] = o / L;
}

// ---------------------------------------------------------------------------
extern "C" void kernel_launch(void* const* d_in, const int* in_sizes, int n_in,
                              void* d_out, int out_size, void* d_ws, size_t ws_size,
                              hipStream_t stream)
{
    const float* main_feat  = (const float*)d_in[0];
    const float* other_feat = (const float*)d_in[1];
    const float* fix_feat   = (const float*)d_in[2];
    const void*  mask       = d_in[3];
    const float* Wq         = (const float*)d_in[4];
    const float* bq         = (const float*)d_in[5];
    const float* Wk         = (const float*)d_in[6];
    const float* bk         = (const float*)d_in[7];
    float* out = (float*)d_out;

    char* ws = (char*)d_ws;
    unsigned short* Qw = (unsigned short*)(ws);                         // 2 MB
    unsigned short* Kw = (unsigned short*)(ws + (1ull << 21));          // 2 MB
    unsigned short* Vt = (unsigned short*)(ws + (2ull << 21));          // 4 MB
    float* Lpart = (float*)(ws + (16ull << 20) + 2048);

    const size_t base = (16ull << 20) + 2048;
    auto need = [&](int ns) {
        return base + (size_t)ns * N_Q * 4 + (size_t)ns * N_Q * DV * 2;
    };
    int nsplit = 1, lgNs = 0;
    if (ws_size >= need(8))      { nsplit = 8; lgNs = 3; }
    else if (ws_size >= need(4)) { nsplit = 4; lgNs = 2; }
    else if (ws_size >= need(2)) { nsplit = 2; lgNs = 1; }

    unsigned short* Opart = (unsigned short*)(Lpart + (size_t)nsplit * N_Q);

    hipLaunchKernelGGL(proj_kernel, dim3(128, 2), dim3(256), 0, stream,
                       main_feat, Wq, bq, other_feat, Wk, bk, Qw, Kw);
    hipLaunchKernelGGL(build_vt_kernel, dim3(128, 4), dim3(256), 0, stream,
                       other_feat, fix_feat, Vt);
    hipLaunchKernelGGL(flash_kernel, dim3(64, nsplit), dim3(512), 0, stream,
                       Qw, Kw, Vt, (const unsigned int*)mask, Opart, Lpart, nsplit, lgNs);
    hipLaunchKernelGGL(combine_kernel, dim3(N_Q), dim3(256), 0, stream,
                       Opart, Lpart, out, nsplit);
}

// Round 12
// 423.163 us; speedup vs baseline: 1.4688x; 1.2648x over previous
//
#include <hip/hip_runtime.h>
#include <hip/hip_bf16.h>
#include <stdint.h>

typedef __attribute__((ext_vector_type(8))) short short8;
typedef __attribute__((ext_vector_type(4))) float floatx4;

#define MFMA32K(a, b, c) __builtin_amdgcn_mfma_f32_16x16x32_bf16(a, b, c, 0, 0, 0)

constexpr int N_Q  = 8192;
constexpr int M_KV = 8192;
constexpr int DMID = 128;
constexpr int DV   = 256;

__device__ __forceinline__ unsigned short f2bf(float x) {
    unsigned u = __float_as_uint(x);
    u += 0x7fffu + ((u >> 16) & 1u);
    return (unsigned short)(u >> 16);
}

__device__ __forceinline__ short8 cvt_f8_bf8(float4 a, float4 b) {
    short8 r;
    r[0] = (short)f2bf(a.x); r[1] = (short)f2bf(a.y);
    r[2] = (short)f2bf(a.z); r[3] = (short)f2bf(a.w);
    r[4] = (short)f2bf(b.x); r[5] = (short)f2bf(b.y);
    r[6] = (short)f2bf(b.z); r[7] = (short)f2bf(b.w);
    return r;
}

// async global->LDS, 16B per lane; lds dst is wave-uniform (HW adds lane*16)
__device__ __forceinline__ void gl_lds16(const unsigned short* g, unsigned short* l) {
    __builtin_amdgcn_global_load_lds(
        (const __attribute__((address_space(1))) unsigned int*)g,
        (__attribute__((address_space(3))) unsigned int*)l, 16, 0, 0);
}

// nonzero-byte -> 4-bit mask (bit i = byte i != 0)
__device__ __forceinline__ unsigned nz4(unsigned x) {
    unsigned nz = (((x & 0x7f7f7f7fu) + 0x7f7f7f7fu) | x) & 0x80808080u;
    unsigned a = (nz >> 7) & 0x01010101u;
    return (a * 0x01020408u) >> 24;
}

// ---------------------------------------------------------------------------
// Projections: dst[row] = src[row] @ W^T + bias, bf16, 16B-unit rotation
// within the row: unit' = (unit + row) & 15.
// ---------------------------------------------------------------------------
__global__ __launch_bounds__(256) void proj_kernel(
    const float* __restrict__ main_feat, const float* __restrict__ Wq, const float* __restrict__ bq,
    const float* __restrict__ other_feat, const float* __restrict__ Wk, const float* __restrict__ bk,
    unsigned short* __restrict__ Qw, unsigned short* __restrict__ Kw)
{
    const float* src;  const float* W;  const float* bias;  unsigned short* dst;
    if (blockIdx.y == 0) { src = main_feat;  W = Wq; bias = bq; dst = Qw; }
    else                 { src = other_feat; W = Wk; bias = bk; dst = Kw; }

    const int wave = threadIdx.x >> 6, lane = threadIdx.x & 63;
    const int n = lane & 15, quad = lane >> 4;
    const int row0 = blockIdx.x * 64 + wave * 16;

    short8 a[8];
    const float* ap = src + (size_t)(row0 + n) * 256 + quad * 8;
#pragma unroll
    for (int ks = 0; ks < 8; ++ks) {
        float4 x0 = *(const float4*)(ap + ks * 32);
        float4 x1 = *(const float4*)(ap + ks * 32 + 4);
        a[ks] = cvt_f8_bf8(x0, x1);
    }

    floatx4 acc[8];
#pragma unroll
    for (int nt = 0; nt < 8; ++nt) acc[nt] = floatx4{0.f, 0.f, 0.f, 0.f};

#pragma unroll
    for (int nt = 0; nt < 8; ++nt) {
        const float* wp = W + (size_t)(nt * 16 + n) * 256 + quad * 8;
#pragma unroll
        for (int ks = 0; ks < 8; ++ks) {
            float4 w0 = *(const float4*)(wp + ks * 32);
            float4 w1 = *(const float4*)(wp + ks * 32 + 4);
            short8 b = cvt_f8_bf8(w0, w1);
            acc[nt] = MFMA32K(a[ks], b, acc[nt]);
        }
    }

#pragma unroll
    for (int nt = 0; nt < 8; ++nt) {
        float bb = bias[nt * 16 + n];
#pragma unroll
        for (int reg = 0; reg < 4; ++reg) {
            int r = row0 + quad * 4 + reg;
            int c = nt * 16 + n;
            int phys = ((((c >> 3) + r) & 15) << 3) | (c & 7);
            dst[(size_t)r * DMID + phys] = f2bf(acc[nt][reg] + bb);
        }
    }
}

// ---------------------------------------------------------------------------
// Vt[d][col(m)] = fix[m] * other[m][d]; col = pc-permutation (kv=32e+16s+4q+j
// -> pc=32e+8q+4s+j) composed with 16B-unit rotation by d per 64-col group.
// ---------------------------------------------------------------------------
__global__ __launch_bounds__(256) void build_vt_kernel(
    const float* __restrict__ other_feat, const float* __restrict__ fix_feat,
    unsigned short* __restrict__ Vt)
{
    __shared__ unsigned short tile[64 * 72];
    const int t = threadIdx.x;
    const int m0 = blockIdx.x * 64, d0 = blockIdx.y * 64;

#pragma unroll
    for (int r = 0; r < 4; ++r) {
        int idx = r * 256 + t;
        int ml = idx >> 4, dl4 = (idx & 15) * 4;
        float4 v = *(const float4*)(other_feat + (size_t)(m0 + ml) * 256 + d0 + dl4);
        float f = fix_feat[m0 + ml];
        tile[(dl4 + 0) * 72 + ml] = f2bf(v.x * f);
        tile[(dl4 + 1) * 72 + ml] = f2bf(v.y * f);
        tile[(dl4 + 2) * 72 + ml] = f2bf(v.z * f);
        tile[(dl4 + 3) * 72 + ml] = f2bf(v.w * f);
    }
    __syncthreads();
#pragma unroll
    for (int r = 0; r < 8; ++r) {
        int dl = r * 8 + (t >> 5);
        int d = d0 + dl;
        int ml = (t & 31) * 2;
        int e = ml >> 5, s = (ml >> 4) & 1, q = (ml >> 2) & 3, j = ml & 3;
        int pc = e * 32 + q * 8 + s * 4 + j;
        int phys = ((((pc >> 3) + d) & 7) << 3) | (pc & 7);
        unsigned int v0 = tile[dl * 72 + ml];
        unsigned int v1 = tile[dl * 72 + ml + 1];
        *(unsigned int*)(Vt + (size_t)d * M_KV + m0 + phys) = v0 | (v1 << 16);
    }
}

// ---------------------------------------------------------------------------
// Flash attention body — 8-wave (512-thread) counted-vmcnt pipeline.
// R11 verified the ordering logic (passed, 3.4 TB/s stream) but
// __launch_bounds__(512,4) capped unified regs at 128/wave -> ~70 regs
// spilled (261 MB scratch writes). This round: (512,2) -> 256 regs/wave,
// zero spill, 8 waves/CU. In-flight per CU: 10 VMEM ops x ~1KB x 8 waves
// = 80 KB >> ~22 KB Little's-law need -> BW stays saturated.
// Per-iteration VMEM per wave, pinned order:
//   Vt(it) DMA [4] ; K(it+1) DMA [2] ; SGB ; compress(it) [counted wait on
//   mask(it), the 4 oldest] ; SGB ; mask(it+1) loads [4] ; SGB
//   QK ; softmax
//   beta: vmcnt(4)+lgkm(0)+barrier  -> drains Vt+K, masks keep flying
//         (vmcnt(0) last iter)
//   PV
//   end:  lgkm(0)+barrier           -> PV reads done before next Vt DMA
// ESZ = mask element size (4: int32/f32 nonzero; 1: bool/uint8).
// BM=128 (8 waves x 16 rows), K double-buffered, Vt single-buffered,
// S^T form, all-16x16x32 MFMA, pc-permuted Vt, KV phase stagger (R8 win).
// LDS 64 KB.
// ---------------------------------------------------------------------------
template<int ESZ>
__device__ __forceinline__ void flash_body(
    const unsigned short* __restrict__ Qw, const unsigned short* __restrict__ Kw,
    const unsigned short* __restrict__ Vt, const unsigned int* __restrict__ mask,
    unsigned short* __restrict__ Opart, float* __restrict__ Lpart,
    int nsplit, int lgNs,
    unsigned short* k_lds /* 2 x 64 x 128 */, unsigned short* vt_lds /* 256 x 64 */)
{
    const int L = blockIdx.x + gridDim.x * blockIdx.y;
    const int ly = L & (nsplit - 1);      // L&7 == XCD id under round-robin
    const int lx = L >> lgNs;             // -> per-XCD L2-resident K/V chunk
    const int chunkLen = M_KV >> lgNs;
    const int mBeg = ly * chunkLen;
    const int iters = chunkLen / 64;
    const int phase = lx & (iters - 1);   // per-block start tile (iters is pow2)
    const int tid = threadIdx.x;
    const int wave = tid >> 6, lane = tid & 63, n = lane & 15, quad = lane >> 4;
    const int qrow0 = lx * 128 + wave * 16;   // 16 q-rows per wave
    constexpr float SC = 0.08838834764831845f * 1.4426950408889634f; // scale*log2(e)

    auto mcol = [&](int it) {
        int idx = it + phase;
        if (idx >= iters) idx -= iters;
        return mBeg + idx * 64;
    };

    // Q fragments (rotated layout: unit' = (unit + row) & 15)
    short8 qf[4];
#pragma unroll
    for (int db = 0; db < 4; ++db) {
        int row = qrow0 + n;
        int phys = (db * 4 + quad + row) & 15;
        qf[db] = *(const short8*)(Qw + (size_t)row * DMID + phys * 8);
    }

    floatx4 Oacc[16];
#pragma unroll
    for (int dt = 0; dt < 16; ++dt) Oacc[dt] = floatx4{0.f, 0.f, 0.f, 0.f};

    float lrow = 0.f;

    // staging invariants (8-wave coverage)
    const unsigned short* kg = Kw + (size_t)(wave * 4 + (lane >> 4)) * DMID + (lane & 15) * 8;
    const unsigned short* vg = Vt + (size_t)(wave * 8 + (lane >> 3)) * M_KV + (lane & 7) * 8;
    const int kqn = quad + n;

    // raw-mask prefetch regs (single q-tile: 4 loads, 16 VGPR)
    uint4    mv4[4];
    unsigned mv1[4];

    auto load_mask = [&](int m0l) {
        const size_t row = (size_t)(qrow0 + n);
        if constexpr (ESZ == 4) {
            const unsigned* mp = mask + row * M_KV + m0l + quad * 4;
#pragma unroll
            for (int kvt = 0; kvt < 4; ++kvt)
                mv4[kvt] = *(const uint4*)(mp + kvt * 16);
        } else {
            const unsigned* mp = mask + row * (M_KV / 4) + (m0l >> 2) + quad;
#pragma unroll
            for (int kvt = 0; kvt < 4; ++kvt)
                mv1[kvt] = mp[kvt * 4];
        }
    };

    // prologue: K(0) DMA [2] (pinned first), mask(0) [4] (pinned after);
    // vmcnt(4) drains K only, masks keep flying into iter 0's compress.
#pragma unroll
    for (int r = 0; r < 2; ++r)
        gl_lds16(kg + (size_t)(mcol(0) + r * 32) * DMID, &k_lds[wave * 512 + r * 4096]);
    __builtin_amdgcn_sched_barrier(0);
    load_mask(mcol(0));
    __builtin_amdgcn_sched_barrier(0);
    asm volatile("s_waitcnt vmcnt(4)\n\ts_barrier" ::: "memory");

    for (int it = 0; it < iters; ++it) {
        const int m0 = mcol(it);
        const unsigned short* kbuf = k_lds + (it & 1) * 8192;

        // ---- issue DMAs (oldest in vmcnt queue after masks(it)) ----
#pragma unroll
        for (int r = 0; r < 4; ++r)                       // Vt(it) [4]
            gl_lds16(vg + (size_t)(r * 64) * M_KV + m0, &vt_lds[wave * 512 + r * 4096]);
        const bool more = (it + 1 < iters);
        if (more) {
            const int m1 = mcol(it + 1);
            unsigned short* knext = k_lds + ((it + 1) & 1) * 8192 + wave * 512;
#pragma unroll
            for (int r = 0; r < 2; ++r)                   // K(it+1) [2]
                gl_lds16(kg + (size_t)(m1 + r * 32) * DMID, knext + r * 4096);
        }
        __builtin_amdgcn_sched_barrier(0);

        // ---- compress mask(it) (loaded LAST iteration; counted wait on the
        // 4 oldest outstanding loads) -> 16 predicate bits ----
        unsigned wq = 0;
        if constexpr (ESZ == 4) {
#pragma unroll
            for (int kvt = 0; kvt < 4; ++kvt) {
                const unsigned* c = (const unsigned*)&mv4[kvt];
#pragma unroll
                for (int j = 0; j < 4; ++j)
                    wq |= (c[j] != 0u ? 1u : 0u) << (kvt * 4 + j);
            }
        } else {
#pragma unroll
            for (int kvt = 0; kvt < 4; ++kvt)
                wq |= nz4(mv1[kvt]) << (kvt * 4);
        }
        __builtin_amdgcn_sched_barrier(0);

        // ---- NOW safe to issue mask(it+1) into mv regs (newest in queue)
        if (more) load_mask(mcol(it + 1));
        __builtin_amdgcn_sched_barrier(0);

        // ---- S^T = K Q^T (kv = 16kvt + 4quad + reg, q = n) ----
        floatx4 ST[4];
        __builtin_amdgcn_s_setprio(1);
#pragma unroll
        for (int kvt = 0; kvt < 4; ++kvt) {
            const int rowoff = (kvt * 16 + n) * DMID;
            short8 a0 = *(const short8*)&kbuf[rowoff + (((kqn + 0) & 15) << 3)];
            short8 a1 = *(const short8*)&kbuf[rowoff + (((kqn + 4) & 15) << 3)];
            short8 a2 = *(const short8*)&kbuf[rowoff + (((kqn + 8) & 15) << 3)];
            short8 a3 = *(const short8*)&kbuf[rowoff + (((kqn + 12) & 15) << 3)];
            floatx4 s = floatx4{0.f, 0.f, 0.f, 0.f};
            s = MFMA32K(a0, qf[0], s);
            s = MFMA32K(a1, qf[1], s);
            s = MFMA32K(a2, qf[2], s);
            s = MFMA32K(a3, qf[3], s);
            ST[kvt] = s;
        }
        __builtin_amdgcn_s_setprio(0);

        // ---- p = exp2(s*SC), 0 where masked; pack to A-frags ----
        short8 pf8[2];
#pragma unroll
        for (int kvt = 0; kvt < 4; ++kvt) {
            int e = kvt >> 1, s = kvt & 1;
            float p[4];
#pragma unroll
            for (int j = 0; j < 4; ++j) {
                float v = __builtin_amdgcn_exp2f(ST[kvt][j] * SC);
                p[j] = ((wq >> (kvt * 4 + j)) & 1u) ? 0.f : v;
                lrow += p[j];
            }
            __hip_bfloat162 h0 = __float22bfloat162_rn(make_float2(p[0], p[1]));
            __hip_bfloat162 h1 = __float22bfloat162_rn(make_float2(p[2], p[3]));
            unsigned u0, u1;
            __builtin_memcpy(&u0, &h0, 4);
            __builtin_memcpy(&u1, &h1, 4);
            ((unsigned*)&pf8[e])[s * 2 + 0] = u0;
            ((unsigned*)&pf8[e])[s * 2 + 1] = u1;
        }

        // beta: drain Vt(it)+K(it+1) (6 oldest of 10), masks stay in flight
        if (more)
            asm volatile("s_waitcnt vmcnt(4) lgkmcnt(0)\n\ts_barrier" ::: "memory");
        else
            asm volatile("s_waitcnt vmcnt(0) lgkmcnt(0)\n\ts_barrier" ::: "memory");

        // ---- O += P V (rotated contiguous b128 from vt_lds) ----
        __builtin_amdgcn_s_setprio(1);
#pragma unroll
        for (int e = 0; e < 2; ++e) {
#pragma unroll
            for (int dt = 0; dt < 16; ++dt) {
                const int vb = (dt * 16 + n) * 64 + (((e * 4 + quad + n) & 7) << 3);
                short8 bv = *(const short8*)&vt_lds[vb];
                Oacc[dt] = MFMA32K(pf8[e], bv, Oacc[dt]);
            }
        }
        __builtin_amdgcn_s_setprio(0);

        // end: all waves' PV reads done before next iteration's Vt DMA writes
        asm volatile("s_waitcnt lgkmcnt(0)\n\ts_barrier" ::: "memory");
    }

    // ---- epilogue: bf16 partials + cross-quad l reduction ----
    const size_t obase = (size_t)ly * N_Q * DV;
#pragma unroll
    for (int dt = 0; dt < 16; ++dt)
#pragma unroll
        for (int reg = 0; reg < 4; ++reg) {
            int gr = qrow0 + quad * 4 + reg;
            Opart[obase + (size_t)gr * DV + dt * 16 + n] = f2bf(Oacc[dt][reg]);
        }
    {
        float r = lrow;
        r += __shfl_xor(r, 16);
        r += __shfl_xor(r, 32);
        if (quad == 0)
            Lpart[ly * N_Q + qrow0 + n] = r;
    }
}

// ---------------------------------------------------------------------------
// Flash kernel: in-device mask-dtype detection (element count can't
// distinguish 1B vs 4B storage host-side), then dispatch to matching body.
// Both bodies share the kernel-scope LDS (64 KB).
// (512,2): 256 unified regs/wave -> no spill (R11's (512,4) capped at 128
// and spilled 261 MB).
// ---------------------------------------------------------------------------
__global__ __launch_bounds__(512, 2) void flash_kernel(
    const unsigned short* __restrict__ Qw, const unsigned short* __restrict__ Kw,
    const unsigned short* __restrict__ Vt, const unsigned int* __restrict__ mask,
    unsigned short* __restrict__ Opart, float* __restrict__ Lpart,
    int nsplit, int lgNs)
{
    __shared__ __align__(16) unsigned short k_lds[2][64 * 128];  // 2 x 16 KB
    __shared__ __align__(16) unsigned short vt_lds[256 * 64];    // 32 KB

    // dtype detect on first 64 words (L2-hot; identical across waves/blocks):
    // f32 1.0 pattern -> 4-byte; word>1 -> packed uint8; else int32 -> 4-byte
    unsigned w0 = mask[threadIdx.x & 63];
    bool isf = (w0 == 0x3f800000u);
    bool isb = (w0 > 1u) && !isf;
    bool wide = (__ballot(isf) != 0ull) || (__ballot(isb) == 0ull);

    if (wide)
        flash_body<4>(Qw, Kw, Vt, mask, Opart, Lpart, nsplit, lgNs,
                      &k_lds[0][0], vt_lds);
    else
        flash_body<1>(Qw, Kw, Vt, mask, Opart, Lpart, nsplit, lgNs,
                      &k_lds[0][0], vt_lds);
}

// ---------------------------------------------------------------------------
// Combine: out = (sum_c O_c) / (sum_c l_c).
// ---------------------------------------------------------------------------
__global__ __launch_bounds__(256) void combine_kernel(
    const unsigned short* __restrict__ Opart, const float* __restrict__ Lpart,
    float* __restrict__ out, int nsplit)
{
    const int row = blockIdx.x, d = threadIdx.x;
    float L = 0.f, o = 0.f;
    for (int c = 0; c < nsplit; ++c) {
        L += Lpart[c * N_Q + row];
        unsigned int b = Opart[((size_t)c * N_Q + row) * DV + d];
        o += __uint_as_float(b << 16);
    }
    out[(size_t)row * DV + d] = o / L;
}

// ---------------------------------------------------------------------------
extern "C" void kernel_launch(void* const* d_in, const int* in_sizes, int n_in,
                              void* d_out, int out_size, void* d_ws, size_t ws_size,
                              hipStream_t stream)
{
    const float* main_feat  = (const float*)d_in[0];
    const float* other_feat = (const float*)d_in[1];
    const float* fix_feat   = (const float*)d_in[2];
    const void*  mask       = d_in[3];
    const float* Wq         = (const float*)d_in[4];
    const float* bq         = (const float*)d_in[5];
    const float* Wk         = (const float*)d_in[6];
    const float* bk         = (const float*)d_in[7];
    float* out = (float*)d_out;

    char* ws = (char*)d_ws;
    unsigned short* Qw = (unsigned short*)(ws);                         // 2 MB
    unsigned short* Kw = (unsigned short*)(ws + (1ull << 21));          // 2 MB
    unsigned short* Vt = (unsigned short*)(ws + (2ull << 21));          // 4 MB
    float* Lpart = (float*)(ws + (16ull << 20) + 2048);

    const size_t base = (16ull << 20) + 2048;
    auto need = [&](int ns) {
        return base + (size_t)ns * N_Q * 4 + (size_t)ns * N_Q * DV * 2;
    };
    int nsplit = 1, lgNs = 0;
    if (ws_size >= need(8))      { nsplit = 8; lgNs = 3; }
    else if (ws_size >= need(4)) { nsplit = 4; lgNs = 2; }
    else if (ws_size >= need(2)) { nsplit = 2; lgNs = 1; }

    unsigned short* Opart = (unsigned short*)(Lpart + (size_t)nsplit * N_Q);

    hipLaunchKernelGGL(proj_kernel, dim3(128, 2), dim3(256), 0, stream,
                       main_feat, Wq, bq, other_feat, Wk, bk, Qw, Kw);
    hipLaunchKernelGGL(build_vt_kernel, dim3(128, 4), dim3(256), 0, stream,
                       other_feat, fix_feat, Vt);
    hipLaunchKernelGGL(flash_kernel, dim3(64, nsplit), dim3(512), 0, stream,
                       Qw, Kw, Vt, (const unsigned int*)mask, Opart, Lpart, nsplit, lgNs);
    hipLaunchKernelGGL(combine_kernel, dim3(N_Q), dim3(256), 0, stream,
                       Opart, Lpart, out, nsplit);
}